// Round 1
// baseline (2404.682 us; speedup 1.0000x reference)
//
#include <hip/hip_runtime.h>
#include <math.h>

#ifndef M_PI
#define M_PI 3.14159265358979323846
#endif

// ---------------------------------------------------------------------------
// TensorNet interaction, fp32.
// Compressed irreducible representation per (n,f): u[9] =
//   { lam, a01, a02, a12, s00, s01, s02, s11, s12 }   (s22 = -s00-s11)
// Slab layout for all node-edge exchanged tensors: [9][N][F] (F contiguous).
// ws: U (9NF), T (9NF), msg (9NF)   = 3 * 57.6 MB = 172.8 MB
// ---------------------------------------------------------------------------

__device__ __forceinline__ float silu_f(float x) {
    return x / (1.0f + __expf(-x));
}

__device__ __forceinline__ void recon(const float u[9], float M[9]) {
    M[0] =  u[0] + u[4];
    M[1] =  u[1] + u[5];
    M[2] =  u[2] + u[6];
    M[3] = -u[1] + u[5];
    M[4] =  u[0] + u[7];
    M[5] =  u[3] + u[8];
    M[6] = -u[2] + u[6];
    M[7] = -u[3] + u[8];
    M[8] =  u[0] - u[4] - u[7];
}

// ---------------------------------------------------------------------------
// K1: per (n,f): Xn = X/(|X|^2+1), decompose -> U slabs [9][N][64]
// block = 256 threads = 4 nodes (wave per node, lane = f)
// ---------------------------------------------------------------------------
__global__ __launch_bounds__(256) void k_node_prep(
    const float* __restrict__ X, float* __restrict__ U, int N)
{
    __shared__ float s_x[2304];
    int tid = threadIdx.x;
    size_t base = (size_t)blockIdx.x * 2304;
    size_t total = (size_t)N * 576;
    for (int idx = tid; idx < 2304; idx += 256) {
        size_t gi = base + idx;
        s_x[idx] = (gi < total) ? X[gi] : 0.f;
    }
    __syncthreads();
    int w = tid >> 6, f = tid & 63;
    int n = blockIdx.x * 4 + w;
    if (n >= N) return;
    float m[9]; float n2 = 0.f;
#pragma unroll
    for (int i = 0; i < 9; ++i) { m[i] = s_x[w * 576 + f * 9 + i]; n2 += m[i] * m[i]; }
    float inv = 1.0f / (n2 + 1.0f);
#pragma unroll
    for (int i = 0; i < 9; ++i) m[i] *= inv;
    float lam = (m[0] + m[4] + m[8]) * (1.f / 3.f);
    size_t slab = (size_t)N * 64;
    size_t t = (size_t)n * 64 + f;
    U[0 * slab + t] = lam;
    U[1 * slab + t] = 0.5f * (m[1] - m[3]);
    U[2 * slab + t] = 0.5f * (m[2] - m[6]);
    U[3 * slab + t] = 0.5f * (m[5] - m[7]);
    U[4 * slab + t] = m[0] - lam;
    U[5 * slab + t] = 0.5f * (m[1] + m[3]);
    U[6 * slab + t] = 0.5f * (m[2] + m[6]);
    U[7 * slab + t] = m[4] - lam;
    U[8 * slab + t] = 0.5f * (m[5] + m[7]);
}

// ---------------------------------------------------------------------------
// Comp GEMM: out[row][g] = sum_f in[row][f] * Wsel[g][f], rows = c*N+n,
// sel: c==0 -> Wa, c in 1..3 -> Wb, c in 4..8 -> Wc.
// block: 64 rows x 64 cols, 256 threads, 4x4 register tiles.
// ---------------------------------------------------------------------------
__global__ __launch_bounds__(256) void k_comp_gemm(
    const float* __restrict__ in, float* __restrict__ out,
    const float* __restrict__ Wa, const float* __restrict__ Wb,
    const float* __restrict__ Wc, int R, int N)
{
    __shared__ float s_a[64 * 68];   // transposed: s_a[k][row], stride 68
    int tid = threadIdx.x;
    int r0 = blockIdx.x * 64;
    for (int idx = tid; idx < 1024; idx += 256) {
        int row = idx >> 4;
        int k4 = (idx & 15) << 2;
        int gr = r0 + row;
        float4 v = make_float4(0.f, 0.f, 0.f, 0.f);
        if (gr < R) v = *(const float4*)(in + (size_t)gr * 64 + k4);
        s_a[(k4 + 0) * 68 + row] = v.x;
        s_a[(k4 + 1) * 68 + row] = v.y;
        s_a[(k4 + 2) * 68 + row] = v.z;
        s_a[(k4 + 3) * 68 + row] = v.w;
    }
    __syncthreads();
    int et = tid >> 4, ct = tid & 15;
    int c0 = ct * 4;
    int rbase = r0 + et * 4;
    float4 acc[4];
#pragma unroll
    for (int cc = 0; cc < 4; ++cc) acc[cc] = make_float4(0.f, 0.f, 0.f, 0.f);

    int cA = r0 / N;
    int rlast = min(r0 + 63, R - 1);
    int cB = rlast / N;
    int gA = (cA == 0) ? 0 : (cA < 4 ? 1 : 2);
    int gB = (cB == 0) ? 0 : (cB < 4 ? 1 : 2);

    if (gA == gB) {
        const float* W = (gA == 0) ? Wa : (gA == 1 ? Wb : Wc);
        for (int k = 0; k < 64; k += 4) {
            float4 a0 = *(const float4*)&s_a[(k + 0) * 68 + et * 4];
            float4 a1 = *(const float4*)&s_a[(k + 1) * 68 + et * 4];
            float4 a2 = *(const float4*)&s_a[(k + 2) * 68 + et * 4];
            float4 a3 = *(const float4*)&s_a[(k + 3) * 68 + et * 4];
#pragma unroll
            for (int cc = 0; cc < 4; ++cc) {
                float4 w4 = *(const float4*)&W[(c0 + cc) * 64 + k];
                acc[cc].x += w4.x * a0.x + w4.y * a1.x + w4.z * a2.x + w4.w * a3.x;
                acc[cc].y += w4.x * a0.y + w4.y * a1.y + w4.z * a2.y + w4.w * a3.y;
                acc[cc].z += w4.x * a0.z + w4.y * a1.z + w4.z * a2.z + w4.w * a3.z;
                acc[cc].w += w4.x * a0.w + w4.y * a1.w + w4.z * a2.w + w4.w * a3.w;
            }
        }
    } else {
        // rare path: block crosses a weight-group boundary (~2 of 3516 blocks)
        const float* Wi[4];
#pragma unroll
        for (int i = 0; i < 4; ++i) {
            int r = min(rbase + i, R - 1);
            int c = r / N;
            int g = (c == 0) ? 0 : (c < 4 ? 1 : 2);
            Wi[i] = (g == 0) ? Wa : (g == 1 ? Wb : Wc);
        }
        for (int k = 0; k < 64; ++k) {
            float a0 = s_a[k * 68 + et * 4 + 0];
            float a1 = s_a[k * 68 + et * 4 + 1];
            float a2 = s_a[k * 68 + et * 4 + 2];
            float a3 = s_a[k * 68 + et * 4 + 3];
#pragma unroll
            for (int cc = 0; cc < 4; ++cc) {
                acc[cc].x += Wi[0][(c0 + cc) * 64 + k] * a0;
                acc[cc].y += Wi[1][(c0 + cc) * 64 + k] * a1;
                acc[cc].z += Wi[2][(c0 + cc) * 64 + k] * a2;
                acc[cc].w += Wi[3][(c0 + cc) * 64 + k] * a3;
            }
        }
    }
    if (rbase + 0 < R) {
        float4 o = make_float4(acc[0].x, acc[1].x, acc[2].x, acc[3].x);
        *(float4*)(out + (size_t)(rbase + 0) * 64 + c0) = o;
    }
    if (rbase + 1 < R) {
        float4 o = make_float4(acc[0].y, acc[1].y, acc[2].y, acc[3].y);
        *(float4*)(out + (size_t)(rbase + 1) * 64 + c0) = o;
    }
    if (rbase + 2 < R) {
        float4 o = make_float4(acc[0].z, acc[1].z, acc[2].z, acc[3].z);
        *(float4*)(out + (size_t)(rbase + 2) * 64 + c0) = o;
    }
    if (rbase + 3 < R) {
        float4 o = make_float4(acc[0].w, acc[1].w, acc[2].w, acc[3].w);
        *(float4*)(out + (size_t)(rbase + 3) * 64 + c0) = o;
    }
}

// ---------------------------------------------------------------------------
// K2: fused edge MLP (32->64->128->192, SiLU, x cutoff) + gather/scatter.
// 64 edges per block, 256 threads. Activations transposed in LDS [c][68].
// Layer-3 output row c = cmp*64 + f  (holds MLP output index f*3+cmp).
// ---------------------------------------------------------------------------
__global__ __launch_bounds__(256) void k_edge(
    const float* __restrict__ radial, const float* __restrict__ d_ij,
    const int* __restrict__ pair,
    const float* __restrict__ W1, const float* __restrict__ b1,
    const float* __restrict__ W2, const float* __restrict__ b2,
    const float* __restrict__ W3, const float* __restrict__ b3,
    const float* __restrict__ T, float* __restrict__ msg,
    int E, int N)
{
    __shared__ float s_act[192 * 68];
    __shared__ float s_C[64];
    __shared__ int s_src[64];
    __shared__ int s_dst[64];
    int tid = threadIdx.x;
    int e0 = blockIdx.x * 64;

    {   // stage rbf transposed: s_act[k][j] = radial[(e0+j)*32+k]
        int j = tid >> 2;
        int kk = (tid & 3) * 8;
        int e = e0 + j;
        float4 v0 = make_float4(0.f, 0.f, 0.f, 0.f), v1 = v0;
        if (e < E) {
            v0 = *(const float4*)(radial + (size_t)e * 32 + kk);
            v1 = *(const float4*)(radial + (size_t)e * 32 + kk + 4);
        }
        s_act[(kk + 0) * 68 + j] = v0.x;
        s_act[(kk + 1) * 68 + j] = v0.y;
        s_act[(kk + 2) * 68 + j] = v0.z;
        s_act[(kk + 3) * 68 + j] = v0.w;
        s_act[(kk + 4) * 68 + j] = v1.x;
        s_act[(kk + 5) * 68 + j] = v1.y;
        s_act[(kk + 6) * 68 + j] = v1.z;
        s_act[(kk + 7) * 68 + j] = v1.w;
    }
    if (tid < 64) {
        int e = e0 + tid;
        float d = (e < E) ? d_ij[e] : 1e9f;
        s_C[tid] = (d < 5.0f) ? 0.5f * (cosf((float)M_PI * d * 0.2f) + 1.0f) : 0.0f;
        s_src[tid] = (e < E) ? pair[e] : 0;
        s_dst[tid] = (e < E) ? pair[(size_t)E + e] : 0;
    }
    __syncthreads();

    int et = tid >> 4, ct = tid & 15;
    int e4 = et * 4;

#define FMA16(ACC, W4, A0, A1, A2, A3)                                  \
    ACC.x += W4.x * A0.x + W4.y * A1.x + W4.z * A2.x + W4.w * A3.x;     \
    ACC.y += W4.x * A0.y + W4.y * A1.y + W4.z * A2.y + W4.w * A3.y;     \
    ACC.z += W4.x * A0.z + W4.y * A1.z + W4.z * A2.z + W4.w * A3.z;     \
    ACC.w += W4.x * A0.w + W4.y * A1.w + W4.z * A2.w + W4.w * A3.w;

    // ---- layer 1: 32 -> 64
    {
        float4 acc1[4];
#pragma unroll
        for (int cc = 0; cc < 4; ++cc) {
            float b = b1[ct * 4 + cc];
            acc1[cc] = make_float4(b, b, b, b);
        }
        for (int k = 0; k < 32; k += 4) {
            float4 a0 = *(const float4*)&s_act[(k + 0) * 68 + e4];
            float4 a1 = *(const float4*)&s_act[(k + 1) * 68 + e4];
            float4 a2 = *(const float4*)&s_act[(k + 2) * 68 + e4];
            float4 a3 = *(const float4*)&s_act[(k + 3) * 68 + e4];
#pragma unroll
            for (int cc = 0; cc < 4; ++cc) {
                float4 w4 = *(const float4*)&W1[(ct * 4 + cc) * 32 + k];
                FMA16(acc1[cc], w4, a0, a1, a2, a3)
            }
        }
        __syncthreads();
#pragma unroll
        for (int cc = 0; cc < 4; ++cc) {
            int c = ct * 4 + cc;
            float4 v = make_float4(silu_f(acc1[cc].x), silu_f(acc1[cc].y),
                                   silu_f(acc1[cc].z), silu_f(acc1[cc].w));
            *(float4*)&s_act[c * 68 + e4] = v;
        }
        __syncthreads();
    }

    // ---- layer 2: 64 -> 128
    {
        float4 acc2[2][4];
#pragma unroll
        for (int co = 0; co < 2; ++co)
#pragma unroll
            for (int cc = 0; cc < 4; ++cc) {
                float b = b2[co * 64 + ct * 4 + cc];
                acc2[co][cc] = make_float4(b, b, b, b);
            }
        for (int k = 0; k < 64; k += 4) {
            float4 a0 = *(const float4*)&s_act[(k + 0) * 68 + e4];
            float4 a1 = *(const float4*)&s_act[(k + 1) * 68 + e4];
            float4 a2 = *(const float4*)&s_act[(k + 2) * 68 + e4];
            float4 a3 = *(const float4*)&s_act[(k + 3) * 68 + e4];
#pragma unroll
            for (int co = 0; co < 2; ++co)
#pragma unroll
                for (int cc = 0; cc < 4; ++cc) {
                    float4 w4 = *(const float4*)&W2[(co * 64 + ct * 4 + cc) * 64 + k];
                    FMA16(acc2[co][cc], w4, a0, a1, a2, a3)
                }
        }
        __syncthreads();
#pragma unroll
        for (int co = 0; co < 2; ++co)
#pragma unroll
            for (int cc = 0; cc < 4; ++cc) {
                int c = co * 64 + ct * 4 + cc;
                float4 v = make_float4(silu_f(acc2[co][cc].x), silu_f(acc2[co][cc].y),
                                       silu_f(acc2[co][cc].z), silu_f(acc2[co][cc].w));
                *(float4*)&s_act[c * 68 + e4] = v;
            }
        __syncthreads();
    }

    // ---- layer 3: 128 -> 192, output stored at row cmp*64 + f
    {
        float4 acc3[3][4];
#pragma unroll
        for (int co = 0; co < 3; ++co)
#pragma unroll
            for (int cc = 0; cc < 4; ++cc) {
                float b = b3[(ct * 4 + cc) * 3 + co];
                acc3[co][cc] = make_float4(b, b, b, b);
            }
        for (int k = 0; k < 128; k += 4) {
            float4 a0 = *(const float4*)&s_act[(k + 0) * 68 + e4];
            float4 a1 = *(const float4*)&s_act[(k + 1) * 68 + e4];
            float4 a2 = *(const float4*)&s_act[(k + 2) * 68 + e4];
            float4 a3 = *(const float4*)&s_act[(k + 3) * 68 + e4];
#pragma unroll
            for (int co = 0; co < 3; ++co)
#pragma unroll
                for (int cc = 0; cc < 4; ++cc) {
                    float4 w4 = *(const float4*)&W3[((ct * 4 + cc) * 3 + co) * 128 + k];
                    FMA16(acc3[co][cc], w4, a0, a1, a2, a3)
                }
        }
        __syncthreads();
        float4 C4 = make_float4(s_C[e4], s_C[e4 + 1], s_C[e4 + 2], s_C[e4 + 3]);
#pragma unroll
        for (int co = 0; co < 3; ++co)
#pragma unroll
            for (int cc = 0; cc < 4; ++cc) {
                int c = co * 64 + ct * 4 + cc;
                float4 v = make_float4(silu_f(acc3[co][cc].x) * C4.x,
                                       silu_f(acc3[co][cc].y) * C4.y,
                                       silu_f(acc3[co][cc].z) * C4.z,
                                       silu_f(acc3[co][cc].w) * C4.w);
                *(float4*)&s_act[c * 68 + e4] = v;
            }
        __syncthreads();
    }
#undef FMA16

    // ---- message pass: wave per edge, lane = f
    {
        int wv = tid >> 6, lane = tid & 63;
        size_t slab = (size_t)N * 64;
        for (int e = wv * 16; e < wv * 16 + 16; ++e) {
            if (e0 + e >= E) break;
            int s = s_src[e], d = s_dst[e];
            float rf0 = s_act[(0 * 64 + lane) * 68 + e];
            float rf1 = s_act[(1 * 64 + lane) * 68 + e];
            float rf2 = s_act[(2 * 64 + lane) * 68 + e];
            size_t bd = (size_t)d * 64 + lane;
            size_t bs = (size_t)s * 64 + lane;
            atomicAdd(&msg[0 * slab + bs], rf0 * T[0 * slab + bd]);
            atomicAdd(&msg[1 * slab + bs], rf1 * T[1 * slab + bd]);
            atomicAdd(&msg[2 * slab + bs], rf1 * T[2 * slab + bd]);
            atomicAdd(&msg[3 * slab + bs], rf1 * T[3 * slab + bd]);
#pragma unroll
            for (int c = 4; c < 9; ++c)
                atomicAdd(&msg[c * slab + bs], rf2 * T[c * slab + bd]);
        }
    }
}

// ---------------------------------------------------------------------------
// K4a: per (n,f): M=recon(msg), Y=recon(T), P=scale*(MY+YM),
//      decompose+normalize -> U2 slabs
// ---------------------------------------------------------------------------
__global__ __launch_bounds__(256) void k_node_mix(
    const float* __restrict__ msg, const float* __restrict__ T,
    const float* __restrict__ charges, float* __restrict__ U2, int N)
{
    int t = blockIdx.x * 256 + threadIdx.x;
    if (t >= N * 64) return;
    int n = t >> 6;
    size_t slab = (size_t)N * 64;
    float um[9], uy[9];
#pragma unroll
    for (int c = 0; c < 9; ++c) { um[c] = msg[c * slab + t]; uy[c] = T[c * slab + t]; }
    float M[9], Y[9];
    recon(um, M);
    recon(uy, Y);
    float P[9];
#pragma unroll
    for (int i = 0; i < 3; ++i)
#pragma unroll
        for (int j = 0; j < 3; ++j) {
            float s = 0.f;
#pragma unroll
            for (int k = 0; k < 3; ++k)
                s += M[i * 3 + k] * Y[k * 3 + j] + Y[i * 3 + k] * M[k * 3 + j];
            P[i * 3 + j] = s;
        }
    float sc = 1.0f + 0.1f * charges[n];
    float nrm = 0.f;
#pragma unroll
    for (int i = 0; i < 9; ++i) { P[i] *= sc; nrm += P[i] * P[i]; }
    float inv = 1.0f / (nrm + 1.0f);
    float lam = (P[0] + P[4] + P[8]) * (1.f / 3.f);
    U2[0 * slab + t] = lam * inv;
    U2[1 * slab + t] = 0.5f * (P[1] - P[3]) * inv;
    U2[2 * slab + t] = 0.5f * (P[2] - P[6]) * inv;
    U2[3 * slab + t] = 0.5f * (P[5] - P[7]) * inv;
    U2[4 * slab + t] = (P[0] - lam) * inv;
    U2[5 * slab + t] = 0.5f * (P[1] + P[3]) * inv;
    U2[6 * slab + t] = 0.5f * (P[2] + P[6]) * inv;
    U2[7 * slab + t] = (P[4] - lam) * inv;
    U2[8 * slab + t] = 0.5f * (P[5] + P[7]) * inv;
}

// ---------------------------------------------------------------------------
// K4c: out = Xn + dX + scale * dX@dX  (Xn recomputed from X; dX = recon(V))
// ---------------------------------------------------------------------------
__global__ __launch_bounds__(256) void k_out(
    const float* __restrict__ V, const float* __restrict__ X,
    const float* __restrict__ charges, float* __restrict__ out, int N)
{
    __shared__ float s_x[2304];
    __shared__ float s_o[2304];
    int tid = threadIdx.x;
    int blk = blockIdx.x;
    size_t base = (size_t)blk * 2304;
    size_t total = (size_t)N * 576;
    for (int idx = tid; idx < 2304; idx += 256) {
        size_t gi = base + idx;
        s_x[idx] = (gi < total) ? X[gi] : 0.f;
    }
    __syncthreads();
    int t = blk * 256 + tid;
    if (t < N * 64) {
        int n = t >> 6;
        int w = tid >> 6, f = tid & 63;
        size_t slab = (size_t)N * 64;
        float m[9]; float n2 = 0.f;
#pragma unroll
        for (int i = 0; i < 9; ++i) { m[i] = s_x[w * 576 + f * 9 + i]; n2 += m[i] * m[i]; }
        float invn = 1.0f / (n2 + 1.0f);
#pragma unroll
        for (int i = 0; i < 9; ++i) m[i] *= invn;   // Xn
        float uv[9];
#pragma unroll
        for (int c = 0; c < 9; ++c) uv[c] = V[c * slab + t];
        float dX[9];
        recon(uv, dX);
        float sc = 1.0f + 0.1f * charges[n];
#pragma unroll
        for (int i = 0; i < 3; ++i)
#pragma unroll
            for (int j = 0; j < 3; ++j) {
                float s = 0.f;
#pragma unroll
                for (int k = 0; k < 3; ++k) s += dX[i * 3 + k] * dX[k * 3 + j];
                s_o[w * 576 + f * 9 + i * 3 + j] = m[i * 3 + j] + dX[i * 3 + j] + sc * s;
            }
    }
    __syncthreads();
    for (int idx = tid; idx < 2304; idx += 256) {
        size_t gi = base + idx;
        if (gi < total) out[gi] = s_o[idx];
    }
}

// ---------------------------------------------------------------------------
extern "C" void kernel_launch(void* const* d_in, const int* in_sizes, int n_in,
                              void* d_out, int out_size, void* d_ws, size_t ws_size,
                              hipStream_t stream)
{
    const float* X       = (const float*)d_in[0];
    const int*   pair    = (const int*)d_in[1];
    const float* dij     = (const float*)d_in[2];
    const float* radial  = (const float*)d_in[3];
    const float* charges = (const float*)d_in[4];
    const float* W1  = (const float*)d_in[5];
    const float* b1  = (const float*)d_in[6];
    const float* W2  = (const float*)d_in[7];
    const float* b2  = (const float*)d_in[8];
    const float* W3  = (const float*)d_in[9];
    const float* b3  = (const float*)d_in[10];
    const float* Wl0 = (const float*)d_in[11];
    const float* Wl1 = (const float*)d_in[12];
    const float* Wl2 = (const float*)d_in[13];
    const float* Wl3 = (const float*)d_in[14];
    const float* Wl4 = (const float*)d_in[15];
    const float* Wl5 = (const float*)d_in[16];

    int N = in_sizes[4];   // atomic_charges: [N]
    int E = in_sizes[2];   // d_ij: [E,1]

    size_t slab9 = (size_t)N * 64 * 9;   // floats per buffer
    float* U   = (float*)d_ws;           // comps, later reused as U2
    float* T   = U + slab9;              // transformed comps
    float* msg = T + slab9;              // message accumulator, later reused as V

    hipMemsetAsync(msg, 0, slab9 * sizeof(float), stream);

    int nb_node = (N + 3) / 4;
    k_node_prep<<<nb_node, 256, 0, stream>>>(X, U, N);

    int R = 9 * N;
    int nb_gemm = (R + 63) / 64;
    k_comp_gemm<<<nb_gemm, 256, 0, stream>>>(U, T, Wl0, Wl1, Wl2, R, N);

    int nb_edge = (E + 63) / 64;
    k_edge<<<nb_edge, 256, 0, stream>>>(radial, dij, pair,
                                        W1, b1, W2, b2, W3, b3, T, msg, E, N);

    float* U2 = U;
    k_node_mix<<<(N * 64 + 255) / 256, 256, 0, stream>>>(msg, T, charges, U2, N);

    float* Vv = msg;
    k_comp_gemm<<<nb_gemm, 256, 0, stream>>>(U2, Vv, Wl3, Wl4, Wl5, R, N);

    k_out<<<(N * 64 + 255) / 256, 256, 0, stream>>>(Vv, X, charges, (float*)d_out, N);
}